// Round 14
// baseline (32.995 us; speedup 1.0000x reference)
//
#include <hip/hip_runtime.h>
#include <hip/hip_bf16.h>

// B=2048, NF=64, FD=32, S=32, D=32, OD=32
typedef __attribute__((ext_vector_type(4)))  _Float16 h4;
typedef __attribute__((ext_vector_type(8)))  _Float16 h8;
typedef __attribute__((ext_vector_type(4)))  float f32x4;
typedef __attribute__((ext_vector_type(16))) float f32x16;
typedef __attribute__((ext_vector_type(4)))  unsigned int u32x4;

__device__ __forceinline__ int sdecode(int sp) { return ((sp & 7) << 2) | (sp >> 3); }

// Fused single kernel. grid 512 = (sp = bid&31, m = bid>>5). All 16 blocks of a
// group share XCD (bid%8 = sp%8) -> producer/consumer data stays in ONE L2, and
// group barriers poll 32 distinct cache lines with RELAXED loads (no inv storm).
__global__ __launch_bounds__(256, 2) void fused_kernel(
    const float* __restrict__ x, const float* __restrict__ Lg,
    const float* __restrict__ Rg, const float* __restrict__ Og,
    const float* __restrict__ bias, float* __restrict__ out,
    _Float16* __restrict__ Rb, char* __restrict__ Opp, char* __restrict__ Tp,
    unsigned* __restrict__ bar)
{
    __shared__ __align__(16) char smem[65536];

    const int bid = blockIdx.x;
    const int sp = bid & 31, m = bid >> 5;
    const int s = sdecode(sp);
    const int t = threadIdx.x, wid = t >> 6, l = t & 63;

    unsigned* cnt1 = bar + sp*64;        // one 128B line per group/phase
    unsigned* cnt2 = bar + sp*64 + 32;

    //================ P1: conv, s-group-local (wave -> which = wid>>1, q = 2m+(wid&1))
    {
        const int which = wid >> 1, q = 2*m + (wid & 1);
        float (*tile)[33] = (float (*)[33])(smem + wid*4352);
        const int tl = l & 31, th = l >> 5;

        if (which == 0) {
            #pragma unroll
            for (int j = 0; j < 16; ++j) {              // tile[n][a] = R[s][q][a][n]
                int ar = 2*j + th;
                tile[tl][ar] = Rg[(((size_t)s*32 + q)*32 + ar)*32 + tl];
            }
        } else {
            #pragma unroll
            for (int j = 0; j < 16; ++j) {              // tile[o][n] = O[s][q][n][o]
                int nr = 2*j + th;
                tile[tl][nr] = Og[(((size_t)s*32 + q)*32 + nr)*32 + tl];
            }
        }
        __syncthreads();
        if (which == 0) {
            _Float16* dst = Rb + ((size_t)s*32 + q)*1024;   // Rb[s][g=q][n][a]
            #pragma unroll
            for (int it = 0; it < 4; ++it) {
                int nr = it*8 + (l >> 3), a0 = (l & 7)*4;
                h4 w;
                #pragma unroll
                for (int k = 0; k < 4; ++k) w[k] = (_Float16)tile[nr][a0 + k];
                *(h4*)(dst + nr*32 + a0) = w;
            }
        } else {
            char* dst = Opp + (size_t)s*65536 + q*2048;     // Opp[s][c8][o][kk]
            int o = l & 31, cq = l >> 5;
            #pragma unroll
            for (int it = 0; it < 2; ++it) {
                int c = it*2 + cq;
                h8 w;
                #pragma unroll
                for (int k = 0; k < 8; ++k) w[k] = (_Float16)tile[o][c*8 + k];
                *(h8*)(dst + c*512 + o*16) = w;
            }
        }
    }
    // ---- group barrier 1 (every wave drains its stores first) ----
    asm volatile("s_waitcnt vmcnt(0) lgkmcnt(0)" ::: "memory");
    __syncthreads();
    if (t == 0) {
        atomicAdd(cnt1, 1u);
        while (__hip_atomic_load(cnt1, __ATOMIC_RELAXED, __HIP_MEMORY_SCOPE_AGENT) < 16u)
            __builtin_amdgcn_s_sleep(16);
    }
    __syncthreads();

    //================ P2: tmake for f = 2m, 2m+1 ================
    {
        const int llo = l & 15, lhi = l >> 4;
        const int ot = wid & 1, kq = wid >> 1;
        const int orow = ot*16 + llo;
        const _Float16* Rbs = Rb + (size_t)s*32768;
        const char* Opps = Opp + (size_t)s*65536;
        char* Wl = smem;

        #pragma unroll
        for (int it = 0; it < 2; ++it) {
            const int f = 2*m + it;
            if (it) __syncthreads();                    // Wl reuse across f

            const float* Lsf = Lg + ((size_t)s*32 + f)*1024;
            h8 bfr[2];
            #pragma unroll
            for (int mt = 0; mt < 2; ++mt)
                #pragma unroll
                for (int j = 0; j < 8; ++j)
                    bfr[mt][j] = (_Float16)Lsf[(8*lhi + j)*32 + mt*16 + llo];

            #pragma unroll 4
            for (int nt = 0; nt < 16; ++nt) {           // GEMM1
                int gnb = (wid*16 + nt)*16;
                h8 af = *(const h8*)(Rbs + (gnb + llo)*32 + 8*lhi);
                int g = gnb >> 5;
                int nbase = (gnb & 31) + 4*lhi;
                #pragma unroll
                for (int mt = 0; mt < 2; ++mt) {
                    f32x4 d = __builtin_amdgcn_mfma_f32_16x16x32_f16(af, bfr[mt], (f32x4)(0.f), 0, 0, 0);
                    int mm = mt*16 + llo;
                    h4 w;
                    #pragma unroll
                    for (int r = 0; r < 4; ++r) w[r] = (_Float16)d[r];
                    int byte = (g*2048 + mm*64 + nbase*2) ^ ((((g & 7) ^ (mm & 7))) << 4);
                    *(h4*)(Wl + byte) = w;
                }
            }
            __syncthreads();

            f32x4 acc0 = (f32x4)(0.f), acc1 = (f32x4)(0.f);
            #pragma unroll 4
            for (int ksl = 0; ksl < 16; ++ksl) {        // GEMM2 (kq 2-way k-split)
                int ks = kq*16 + ksl;
                h8 bf = *(const h8*)(Opps + (ks*4 + lhi)*512 + orow*16);
                {
                    int grow = llo;
                    int byte = (grow*2048 + ks*64 + lhi*16) ^ ((((grow & 7) ^ (ks & 7))) << 4);
                    h8 af = *(const h8*)(Wl + byte);
                    acc0 = __builtin_amdgcn_mfma_f32_16x16x32_f16(af, bf, acc0, 0, 0, 0);
                }
                {
                    int grow = 16 + llo;
                    int byte = (grow*2048 + ks*64 + lhi*16) ^ ((((grow & 7) ^ (ks & 7))) << 4);
                    h8 af = *(const h8*)(Wl + byte);
                    acc1 = __builtin_amdgcn_mfma_f32_16x16x32_f16(af, bf, acc1, 0, 0, 0);
                }
            }
            __syncthreads();
            if (kq == 1) {
                *(f32x4*)(Wl + ((ot*2 + 0)*64 + l)*16) = acc0;
                *(f32x4*)(Wl + ((ot*2 + 1)*64 + l)*16) = acc1;
            }
            __syncthreads();
            if (kq == 0) {
                acc0 += *(const f32x4*)(Wl + ((ot*2 + 0)*64 + l)*16);
                acc1 += *(const f32x4*)(Wl + ((ot*2 + 1)*64 + l)*16);
                char* Tps = Tp + (size_t)s*65536;
                h4 w0, w1;
                #pragma unroll
                for (int r = 0; r < 4; ++r) { w0[r] = (_Float16)acc0[r]; w1[r] = (_Float16)acc1[r]; }
                *(h4*)(Tps + (f*2 + 0)*1024 + orow*32 + lhi*8) = w0;
                *(h4*)(Tps + (f*2 + 1)*1024 + orow*32 + lhi*8) = w1;
            }
        }
    }

    //================ x prefetch (issued pre-barrier; vmcnt(12) keeps them flying)
    const int lo5 = l & 31, hi = l >> 5;
    const int b0 = m * 128;
    const float* xrow = x + (size_t)(b0 + wid*32 + lo5)*2048 + s*64;
    asm volatile("" ::: "memory");                      // keep loads after P2 stores
    float4 xlv[8];
    #pragma unroll
    for (int i = 0; i < 8; ++i) xlv[i] = *(const float4*)(xrow + i*4);
    const float* xrp = xrow + 32 + hi*8;
    float4 xr00 = *(const float4*)(xrp);
    float4 xr01 = *(const float4*)(xrp + 4);
    float4 xr10 = *(const float4*)(xrp + 16);
    float4 xr11 = *(const float4*)(xrp + 20);

    // ---- group barrier 2: drain all but the 12 newest (the x loads) ----
    asm volatile("s_waitcnt vmcnt(12) lgkmcnt(0)" ::: "memory");
    __syncthreads();
    if (t == 0) {
        atomicAdd(cnt2, 1u);
        while (__hip_atomic_load(cnt2, __ATOMIC_RELAXED, __HIP_MEMORY_SCOPE_AGENT) < 16u)
            __builtin_amdgcn_s_sleep(16);
    }
    __syncthreads();

    //================ P3: main (v3 structure; T[s] now L2-hot) ================
    {
        char* Tl = smem;
        const char* Tps = Tp + (size_t)s*65536;

        u32x4 tv[8];
        #pragma unroll
        for (int i = 0; i < 8; ++i)
            tv[i] = *(const u32x4*)(Tps + (i*256 + t)*16);
        #pragma unroll
        for (int i = 0; i < 8; ++i)
            *(u32x4*)(Tl + (i*256 + t)*16) = tv[i];
        #pragma unroll
        for (int i = 0; i < 8; ++i)
            tv[i] = *(const u32x4*)(Tps + ((i + 8)*256 + t)*16);

        // convert x to f16 (overlaps second staging batch)
        h4 xlh[8];
        #pragma unroll
        for (int i = 0; i < 8; ++i) {
            xlh[i][0] = (_Float16)xlv[i].x; xlh[i][1] = (_Float16)xlv[i].y;
            xlh[i][2] = (_Float16)xlv[i].z; xlh[i][3] = (_Float16)xlv[i].w;
        }
        h8 xr_a, xr_b;
        xr_a[0] = (_Float16)xr00.x; xr_a[1] = (_Float16)xr00.y;
        xr_a[2] = (_Float16)xr00.z; xr_a[3] = (_Float16)xr00.w;
        xr_a[4] = (_Float16)xr01.x; xr_a[5] = (_Float16)xr01.y;
        xr_a[6] = (_Float16)xr01.z; xr_a[7] = (_Float16)xr01.w;
        xr_b[0] = (_Float16)xr10.x; xr_b[1] = (_Float16)xr10.y;
        xr_b[2] = (_Float16)xr10.z; xr_b[3] = (_Float16)xr10.w;
        xr_b[4] = (_Float16)xr11.x; xr_b[5] = (_Float16)xr11.y;
        xr_b[6] = (_Float16)xr11.z; xr_b[7] = (_Float16)xr11.w;

        #pragma unroll
        for (int i = 0; i < 8; ++i)
            *(u32x4*)(Tl + ((i + 8)*256 + t)*16) = tv[i];
        __syncthreads();

        // K loop: 64 steps, 1 ds_read_b128 + 1 MFMA, acc ILP=2
        f32x16 acc_e = (f32x16)(0.f), acc_o = (f32x16)(0.f);
        #pragma unroll
        for (int ksl = 0; ksl < 64; ++ksl) {
            h8 bf = *(const h8*)(Tl + ksl*1024 + lo5*32 + hi*16);
            _Float16 xs = xlh[ksl >> 3][(ksl >> 1) & 3];
            if (ksl & 1) {
                h8 z = xr_b * xs;
                acc_o = __builtin_amdgcn_mfma_f32_32x32x16_f16(z, bf, acc_o, 0, 0, 0);
            } else {
                h8 z = xr_a * xs;
                acc_e = __builtin_amdgcn_mfma_f32_32x32x16_f16(z, bf, acc_e, 0, 0, 0);
            }
        }
        f32x16 acc = acc_e + acc_o;

        // epilogue: stash in Tl (dead), vectorized full-line f32x4 stores
        __syncthreads();
        #pragma unroll
        for (int r = 0; r < 16; ++r) {
            int row = (r & 3) + 8*(r >> 2) + 4*hi;      // 32x32 C/D row map
            *(float*)(Tl + wid*4096 + row*128 + lo5*4) = acc[r];
        }
        __syncthreads();

        const float* bias_s = bias + s*32;
        #pragma unroll
        for (int i = 0; i < 4; ++i) {
            int u = i*256 + t;
            int row = u >> 3, colq = u & 7;
            f32x4 v = *(const f32x4*)(Tl + u*16);
            f32x4 bv = *(const f32x4*)(bias_s + colq*4);
            *(f32x4*)(out + (size_t)(b0 + row)*1024 + s*32 + colq*4) = v + bv;
        }
    }
}

extern "C" void kernel_launch(void* const* d_in, const int* in_sizes, int n_in,
                              void* d_out, int out_size, void* d_ws, size_t ws_size,
                              hipStream_t stream) {
    const float* x    = (const float*)d_in[0];
    const float* L    = (const float*)d_in[1];
    const float* R    = (const float*)d_in[2];
    const float* O    = (const float*)d_in[3];
    const float* bias = (const float*)d_in[4];
    float* out = (float*)d_out;

    _Float16* Rb  = (_Float16*)d_ws;                     // 2 MB
    char*     Opp = (char*)d_ws + 2097152;               // 2 MB
    char*     Tp  = (char*)d_ws + 4194304;               // 2 MB
    unsigned* bar = (unsigned*)((char*)d_ws + 6291456);  // 32 groups x 2 x 128B

    hipMemsetAsync(bar, 0, 8192, stream);
    fused_kernel<<<dim3(512), dim3(256), 0, stream>>>(x, L, R, O, bias, out,
                                                      Rb, Opp, Tp, bar);
}